// Round 18
// baseline (206.451 us; speedup 1.0000x reference)
//
#include <hip/hip_runtime.h>
#include <hip/hip_bf16.h>
#include <stdint.h>

// ---------------------------------------------------------------------------
// Block: LN -> [q,k,v,p] = h @ w_in^T -> key-smear -> causal attn w/ learned
// ALiBi -> o * silu(p) -> @ w_out^T -> LN.   B=2 L=2048 D=1024 H=16 Dh=128.
// Internal compute in bf16 MFMA.
// ---------------------------------------------------------------------------

typedef __bf16 bf16;
typedef bf16  bf16x8 __attribute__((ext_vector_type(8)));
typedef bf16  bf16x4 __attribute__((ext_vector_type(4)));
typedef float f32x4  __attribute__((ext_vector_type(4)));

#define SEQ   2048
#define NBATC 2

__device__ __forceinline__ void gld_lds16(const bf16* g, bf16* l) {
  __builtin_amdgcn_global_load_lds((const __attribute__((address_space(1))) void*)g,
                                   (__attribute__((address_space(3))) void*)l, 16, 0, 0);
}

// ---------------- device helpers -------------------------------------------
__device__ __forceinline__ void cvt8(const float* __restrict__ in,
                                     bf16* __restrict__ out, int t) {
  const float4* p = (const float4*)in + (size_t)t * 2;
  float4 a = p[0], b = p[1];
  bf16x8 o;
  o[0] = (bf16)a.x; o[1] = (bf16)a.y; o[2] = (bf16)a.z; o[3] = (bf16)a.w;
  o[4] = (bf16)b.x; o[5] = (bf16)b.y; o[6] = (bf16)b.z; o[7] = (bf16)b.w;
  *((bf16x8*)out + t) = o;
}

// ---------------- fused prepass: cvt(w_in) | cvt(w_out) | ln_in -------------
__global__ __launch_bounds__(256) void prepass_kernel(const float* __restrict__ x,
    const float* __restrict__ w_in, const float* __restrict__ w_out,
    const float* __restrict__ gamma, const float* __restrict__ beta,
    bf16* __restrict__ hb, bf16* __restrict__ w_in_b, bf16* __restrict__ w_out_b) {
  const int blk = blockIdx.x;
  const int tid = threadIdx.x;
  if (blk < 4096) {
    cvt8(w_in, w_in_b, blk * 256 + tid);
    return;
  }
  if (blk < 5120) {
    cvt8(w_out, w_out_b, (blk - 4096) * 256 + tid);
    return;
  }
  const int row = blk - 5120;
  float4 v = *(const float4*)(x + (size_t)row * 1024 + tid * 4);
  float s  = v.x + v.y + v.z + v.w;
  float ss = v.x * v.x + v.y * v.y + v.z * v.z + v.w * v.w;
#pragma unroll
  for (int m = 1; m < 64; m <<= 1) { s += __shfl_xor(s, m, 64); ss += __shfl_xor(ss, m, 64); }
  __shared__ float red[8];
  if ((tid & 63) == 0) { red[tid >> 6] = s; red[(tid >> 6) + 4] = ss; }
  __syncthreads();
  s  = red[0] + red[1] + red[2] + red[3];
  ss = red[4] + red[5] + red[6] + red[7];
  const float mu  = s * (1.f / 1024.f);
  const float inv = rsqrtf(ss * (1.f / 1024.f) - mu * mu + 1e-5f);
  float4 g  = *(const float4*)(gamma + tid * 4);
  float4 bb = *(const float4*)(beta  + tid * 4);
  bf16* o = hb + (size_t)row * 1024 + tid * 4;
  o[0] = (bf16)((v.x - mu) * inv * g.x + bb.x);
  o[1] = (bf16)((v.y - mu) * inv * g.y + bb.y);
  o[2] = (bf16)((v.z - mu) * inv * g.z + bb.z);
  o[3] = (bf16)((v.w - mu) * inv * g.w + bb.w);
}

// ---------------- final LayerNorm: sums split-K partials yb0+yb1 ------------
__global__ __launch_bounds__(256) void ln_kernel(const float* __restrict__ y0,
    const float* __restrict__ y1, const float* __restrict__ gamma,
    const float* __restrict__ beta, float* __restrict__ out) {
  const int row = blockIdx.x;
  const int tid = threadIdx.x;
  float4 a = *(const float4*)(y0 + (size_t)row * 1024 + tid * 4);
  float4 c = *(const float4*)(y1 + (size_t)row * 1024 + tid * 4);
  float4 v = {a.x + c.x, a.y + c.y, a.z + c.z, a.w + c.w};
  float s  = v.x + v.y + v.z + v.w;
  float ss = v.x * v.x + v.y * v.y + v.z * v.z + v.w * v.w;
#pragma unroll
  for (int m = 1; m < 64; m <<= 1) { s += __shfl_xor(s, m, 64); ss += __shfl_xor(ss, m, 64); }
  __shared__ float red[8];
  if ((tid & 63) == 0) { red[tid >> 6] = s; red[(tid >> 6) + 4] = ss; }
  __syncthreads();
  s  = red[0] + red[1] + red[2] + red[3];
  ss = red[4] + red[5] + red[6] + red[7];
  const float mu  = s * (1.f / 1024.f);
  const float inv = rsqrtf(ss * (1.f / 1024.f) - mu * mu + 1e-5f);
  float4 g  = *(const float4*)(gamma + tid * 4);
  float4 bb = *(const float4*)(beta  + tid * 4);
  float* o = out + (size_t)row * 1024 + tid * 4;
  o[0] = (v.x - mu) * inv * g.x + bb.x;
  o[1] = (v.y - mu) * inv * g.y + bb.y;
  o[2] = (v.z - mu) * inv * g.z + bb.z;
  o[3] = (v.w - mu) * inv * g.w + bb.w;
}

// ---------------- fused key-smear (XOR-swizzled ksm) + V transpose ----------
__global__ __launch_bounds__(256) void prep_kernel(const bf16* __restrict__ qkvp,
    const float* __restrict__ smf, bf16* __restrict__ ksm, bf16* __restrict__ vt) {
  __shared__ bf16 T[128][72];
  const int kt = blockIdx.x, bh = blockIdx.y;
  const int b = bh >> 4, h = bh & 15;
  const int t = threadIdx.x;

  {
    int i = t >> 2, d0 = (t & 3) * 32;
    const bf16* src = qkvp + (size_t)(b * SEQ + kt * 64 + i) * 8192 + 4096 + h * 128 + d0;
#pragma unroll
    for (int m = 0; m < 4; m++) {
      bf16x8 v8 = *(const bf16x8*)(src + m * 8);
#pragma unroll
      for (int e = 0; e < 8; e++) T[d0 + m * 8 + e][i] = v8[e];
    }
  }

  {
    float sm = 1.f / (1.f + __expf(-smf[h]));
#pragma unroll
    for (int j = 0; j < 4; j++) {
      int c  = j * 256 + t;
      int il = c >> 4, d8 = c & 15;
      int i  = kt * 64 + il;
      const bf16* base = qkvp + (size_t)(b * SEQ + i) * 8192 + 2048 + h * 128 + d8 * 8;
      bf16x8 cur = *(const bf16x8*)base;
      bf16x8 prv = cur;
      if (i > 0) prv = *(const bf16x8*)(base - 8192);
      bf16x8 o;
#pragma unroll
      for (int e = 0; e < 8; e++) {
        float pv = (i > 0) ? (float)prv[e] : 0.f;
        o[e] = (bf16)((1.f - sm) * (float)cur[e] + sm * pv);
      }
      size_t idx = ((size_t)bh * SEQ + i) * 128 + ((d8 * 8) ^ ((i & 7) << 3));
      *(bf16x8*)(ksm + idx) = o;
    }
  }

  __syncthreads();
  {
    int d = t >> 1, i0 = (t & 1) * 32;
    bf16* dst = vt + (size_t)bh * (SEQ * 128) + (size_t)kt * 8192 + d * 64;
#pragma unroll
    for (int m = 0; m < 4; m++) {
      bf16x8 v8 = *(const bf16x8*)&T[d][i0 + m * 8];
      *(bf16x8*)(dst + (((i0 + m * 8)) ^ ((d & 7) << 3))) = v8;
    }
  }
}

// ---------------- GEMM 256x256 tile, BK=32, 4-ring, 16 waves ----------------
// Schedule mirrors the PROVEN attn r13 loop: per barrier pair, stage tiles
// tp+2,tp+3 (1 gld_lds per matrix per tile per thread), counted vmcnt(4)
// (waits only tp/tp+1's loads; 2 tiles stay in flight), barrier, compute
// tp then tp+1 (16 MFMA/wave each), lgkm(0), barrier.  BK=32 swizzle:
// col ^= (row&3)<<3 both-sides (4-way worst-case aliasing, accepted).
__global__ __launch_bounds__(1024, 4) void gemm256(const bf16* __restrict__ A,
    const bf16* __restrict__ Bt, bf16* __restrict__ C, int M, int N, int K,
    int RX, int SX, int SY) {
  __shared__ bf16 As[4][256 * 32];
  __shared__ bf16 Bs[4][256 * 32];
  const int w   = blockIdx.x;
  const int xcd = w & 7, idx = w >> 3;
  const int rx = xcd % RX, ry = xcd / RX;
  const int bx = rx * SX + idx % SX;
  const int by = ry * SY + idx / SX;
  const int tid  = threadIdx.x;
  const int lane = tid & 63, wid = tid >> 6;      // wid 0..15
  const int l4 = lane >> 4, l16 = lane & 15;
  const int wr = wid >> 2, wc = wid & 3;          // 4 x 4 waves
  const int rowBase = by * 256, colBase = bx * 256;
  const int NT = K >> 5;                          // 32 tiles of BK=32

  f32x4 acc[4][4];
  const f32x4 z = {0.f, 0.f, 0.f, 0.f};
#pragma unroll
  for (int i = 0; i < 4; i++)
#pragma unroll
    for (int j = 0; j < 4; j++) acc[i][j] = z;

  // stage one BK=32 tile: 1024 chunks of 16B per matrix, 1 chunk/thread each
  auto stage = [&](int t_, int buf) {
    const int k0  = t_ * 32;
    const int row = tid >> 2;              // 0..255
    const int sc  = ((tid & 3) * 8) ^ ((row & 3) << 3);   // pre-swizzled col
    gld_lds16(A  + (size_t)(rowBase + row) * K + k0 + sc, &As[buf][tid * 8]);
    gld_lds16(Bt + (size_t)(colBase + row) * K + k0 + sc, &Bs[buf][tid * 8]);
  };

  auto tilec = [&](const bf16* a_, const bf16* b_) {
    bf16x8 bfr[4];
#pragma unroll
    for (int ni = 0; ni < 4; ++ni) {
      const int br = wc * 64 + ni * 16 + l16;
      bfr[ni] = *(const bf16x8*)&b_[br * 32 + ((l4 * 8) ^ ((br & 3) << 3))];
    }
#pragma unroll
    for (int mi = 0; mi < 4; ++mi) {
      const int ar = wr * 64 + mi * 16 + l16;
      bf16x8 af = *(const bf16x8*)&a_[ar * 32 + ((l4 * 8) ^ ((ar & 3) << 3))];
#pragma unroll
      for (int ni = 0; ni < 4; ++ni)
        acc[mi][ni] = __builtin_amdgcn_mfma_f32_16x16x32_bf16(af, bfr[ni], acc[mi][ni], 0, 0, 0);
    }
  };

  stage(0, 0);
  stage(1, 1);
  for (int tp = 0; tp < NT; tp += 2) {
    if (tp + 2 < NT) {
      stage(tp + 2, (tp + 2) & 3);
      stage(tp + 3, (tp + 3) & 3);
      asm volatile("s_waitcnt vmcnt(4)" ::: "memory");   // tp, tp+1 landed
    } else {
      asm volatile("s_waitcnt vmcnt(0)" ::: "memory");
    }
    __builtin_amdgcn_sched_barrier(0);
    __builtin_amdgcn_s_barrier();
    tilec(&As[tp & 3][0],       &Bs[tp & 3][0]);
    tilec(&As[(tp + 1) & 3][0], &Bs[(tp + 1) & 3][0]);
    asm volatile("s_waitcnt lgkmcnt(0)" ::: "memory");   // LDS reads done
    __builtin_amdgcn_s_barrier();                        // before overwrite
  }

#pragma unroll
  for (int mi = 0; mi < 4; ++mi)
#pragma unroll
    for (int ni = 0; ni < 4; ++ni) {
      int row = rowBase + wr * 64 + mi * 16 + l4 * 4;
      int col = colBase + wc * 64 + ni * 16 + l16;
#pragma unroll
      for (int r = 0; r < 4; ++r)
        C[(size_t)(row + r) * N + col] = (bf16)acc[mi][ni][r];
    }
}

// ---------------- GEMM 128x128 tile, BK=64, split-K=2 (for gemm2) -----------
__global__ __launch_bounds__(256, 2) void gemm128(const bf16* __restrict__ A,
    const bf16* __restrict__ Bt, float* __restrict__ C, int M, int N, int K,
    int RX, int SX, int SY) {
  __shared__ bf16 As[2][128 * 64];
  __shared__ bf16 Bs[2][128 * 64];
  const int w   = blockIdx.x & 255;
  const int ksl = blockIdx.x >> 8;         // K-slice 0/1
  const int xcd = w & 7, idx = w >> 3;
  const int rx = xcd % RX, ry = xcd / RX;
  const int bx = rx * SX + idx % SX;
  const int by = ry * SY + idx / SX;
  const int tid  = threadIdx.x;
  const int lane = tid & 63, wid = tid >> 6;
  const int l4 = lane >> 4, l16 = lane & 15;
  const int wr = wid >> 1, wc = wid & 1;
  const int rowBase = by * 128, colBase = bx * 128;
  const int KH = K >> 1;                   // 1024
  const int kbase = ksl * KH;
  const int NT = KH >> 6;                  // 16
  float* Cp = C + (size_t)ksl * M * N;

  f32x4 acc[4][4];
  const f32x4 z = {0.f, 0.f, 0.f, 0.f};
#pragma unroll
  for (int i = 0; i < 4; i++)
#pragma unroll
    for (int j = 0; j < 4; j++) acc[i][j] = z;

  auto stage = [&](int t_, int buf) {      // 8 gld_lds per thread
    const int k0 = kbase + t_ * 64;
#pragma unroll
    for (int j = 0; j < 4; ++j) {
      const int c   = j * 256 + tid;       // 1024 chunks of 16B per array
      const int row = c >> 3;              // 0..127
      const int sc  = ((c & 7) * 8) ^ ((row & 7) << 3);
      gld_lds16(A  + (size_t)(rowBase + row) * K + k0 + sc, &As[buf][c * 8]);
      gld_lds16(Bt + (size_t)(colBase + row) * K + k0 + sc, &Bs[buf][c * 8]);
    }
  };

  stage(0, 0);
  for (int t = 0; t < NT; ++t) {
    const int cur = t & 1;
    if (t + 1 < NT) {
      stage(t + 1, cur ^ 1);
      asm volatile("s_waitcnt vmcnt(8)" ::: "memory");   // tile t landed
    } else {
      asm volatile("s_waitcnt vmcnt(0)" ::: "memory");
    }
    __builtin_amdgcn_sched_barrier(0);
    __builtin_amdgcn_s_barrier();
    const bf16* a_ = &As[cur][0];
    const bf16* b_ = &Bs[cur][0];
#pragma unroll
    for (int ks = 0; ks < 2; ++ks) {
      bf16x8 bfr[4];
#pragma unroll
      for (int ni = 0; ni < 4; ++ni) {
        const int br = wc * 64 + ni * 16 + l16;
        bfr[ni] = *(const bf16x8*)&b_[br * 64 + ((ks * 32 + l4 * 8) ^ ((br & 7) << 3))];
      }
#pragma unroll
      for (int mi = 0; mi < 4; ++mi) {
        const int ar = wr * 64 + mi * 16 + l16;
        bf16x8 af = *(const bf16x8*)&a_[ar * 64 + ((ks * 32 + l4 * 8) ^ ((ar & 7) << 3))];
#pragma unroll
        for (int ni = 0; ni < 4; ++ni)
          acc[mi][ni] = __builtin_amdgcn_mfma_f32_16x16x32_bf16(af, bfr[ni], acc[mi][ni], 0, 0, 0);
      }
    }
    asm volatile("s_waitcnt lgkmcnt(0)" ::: "memory");
    __builtin_amdgcn_s_barrier();
  }

#pragma unroll
  for (int mi = 0; mi < 4; ++mi)
#pragma unroll
    for (int ni = 0; ni < 4; ++ni) {
      int row = rowBase + wr * 64 + mi * 16 + l4 * 4;
      int col = colBase + wc * 64 + ni * 16 + l16;
#pragma unroll
      for (int r = 0; r < 4; ++r)
        Cp[(size_t)(row + r) * N + col] = acc[mi][ni][r];
    }
}

// ---------------- flash attention + ALiBi + causal + silu-gate --------------
// [round-13 proven: 78.8us — DO NOT RESTRUCTURE]  256 blocks = 1/CU.
// Block = (bh, pair p): strips qt=15-p then qt=p.  4-buffer LDS ring, TWO
// tiles per barrier pair, counted vmcnt(8).  Swapped-QK^T.  ALiBi window skip.
__global__ __launch_bounds__(512, 2) void attn_kernel(const bf16* __restrict__ qkvp,
    const bf16* __restrict__ ksm, const bf16* __restrict__ vt,
    const float* __restrict__ slopes, bf16* __restrict__ gated) {
  const int w   = blockIdx.x;              // 256 = 8 xcd * 4 bh * 8 pairs
  const int xcd = w & 7;
  const int bh  = xcd * 4 + ((w >> 3) & 3);
  const int pr  = w >> 5;                  // 0..7
  const int b   = bh >> 4, h = bh & 15;
  const int tid = threadIdx.x, wid = tid >> 6, lane = tid & 63;
  const int l4 = lane >> 4, l16 = lane & 15;
  const int swz = (l16 & 7) << 3;
  const float LOG2E = 1.44269504f;
  const float s2 = 0.08838834764831845f * LOG2E;   // (1/sqrt(128))*log2e
  const float slopeL = slopes[h] * LOG2E;

  __shared__ bf16 Kb[4][64 * 128];
  __shared__ bf16 Vb[4][64 * 128];
  __shared__ bf16 P_lds[128 * 64];  // [qrow(128)][k ^ ((qrow&7)<<3)], wave-priv

  const bf16* ksmB = ksm + (size_t)bh * SEQ * 128;
  const bf16* vtB  = vt  + (size_t)bh * SEQ * 128;

  auto stage = [&](int kt, int bsel) {     // 4 loads/thread
#pragma unroll
    for (int j = 0; j < 2; j++) {
      const int c = j * 512 + tid;         // 1024 chunks of 16B
      gld_lds16(ksmB + (size_t)kt * 8192 + c * 8, &Kb[bsel][c * 8]);
      gld_lds16(vtB  + (size_t)kt * 8192 + c * 8, &Vb[bsel][c * 8]);
    }
  };

  auto run_strip = [&](int qtile) {
    const int nt = 2 * qtile + 2;
    int kt0 = 0;
    if (slopeL > 1e-6f) {
      const int W = (int)(64.f / slopeL + 128.f);
      const int wlim = qtile * 128 - W - 63;
      if (wlim > 0) kt0 = (wlim >> 6) & ~1;      // even, >= 0, < nt
    }
    const int iq = qtile * 128 + wid * 16 + l16;   // this lane's q-row
    bf16x8 qf[4];
    {
      const bf16* qrow = qkvp + (size_t)(b * SEQ + iq) * 8192 + h * 128;
#pragma unroll
      for (int kb = 0; kb < 4; kb++) qf[kb] = *(const bf16x8*)(qrow + kb * 32 + l4 * 8);
    }
    f32x4 oacc[8];   // oacc[df][r] = O[iq][df*16 + l4*4 + r]
    const f32x4 z = {0.f, 0.f, 0.f, 0.f};
#pragma unroll
    for (int i = 0; i < 8; i++) oacc[i] = z;
    float m2 = -1e38f, lpart = 0.f;

    auto tile = [&](int t, const bf16* K_, const bf16* V_) {
      f32x4 sacc[4];
#pragma unroll
      for (int jf = 0; jf < 4; jf++) {
        f32x4 a = z;
#pragma unroll
        for (int kb = 0; kb < 4; kb++) {
          bf16x8 kf = *(const bf16x8*)&K_[(jf * 16 + l16) * 128 + ((kb * 32 + l4 * 8) ^ swz)];
          a = __builtin_amdgcn_mfma_f32_16x16x32_bf16(kf, qf[kb], a, 0, 0, 0);
        }
        sacc[jf] = a;
      }

      const bool diag = (t >= 2 * qtile);
      const int kbase = t * 64 + l4 * 4;
#pragma unroll
      for (int jf = 0; jf < 4; jf++) {
#pragma unroll
        for (int r = 0; r < 4; r++) {
          int j = kbase + jf * 16 + r;
          float v = fmaf(sacc[jf][r], s2, (float)j * slopeL);
          if (diag && j > iq) v = -1e38f;
          sacc[jf][r] = v;
        }
      }

      float mx = sacc[0][0];
#pragma unroll
      for (int jf = 0; jf < 4; jf++)
#pragma unroll
        for (int r = 0; r < 4; r++) mx = fmaxf(mx, sacc[jf][r]);
      mx = fmaxf(mx, __shfl_xor(mx, 16, 64));
      mx = fmaxf(mx, __shfl_xor(mx, 32, 64));

      if (__any(mx > m2 + 14.f)) {         // uniform defer-max rescale
        float mnew  = fmaxf(m2, mx);
        float alpha = __builtin_amdgcn_exp2f(m2 - mnew);
        m2 = mnew;
        lpart *= alpha;
#pragma unroll
        for (int df = 0; df < 8; df++) oacc[df] *= alpha;
      }

      float rs = 0.f;
#pragma unroll
      for (int jf = 0; jf < 4; jf++) {
        bf16x4 pw;
#pragma unroll
        for (int r = 0; r < 4; r++) {
          float pe = __builtin_amdgcn_exp2f(sacc[jf][r] - m2);
          rs += pe;
          pw[r] = (bf16)pe;
        }
        *(bf16x4*)&P_lds[(wid * 16 + l16) * 64 + ((jf * 16 + l4 * 4) ^ swz)] = pw;
      }
      lpart += rs;

#pragma unroll
      for (int kb2 = 0; kb2 < 2; ++kb2) {
        bf16x8 pf = *(const bf16x8*)&P_lds[(wid * 16 + l16) * 64 + ((kb2 * 32 + l4 * 8) ^ swz)];
#pragma unroll
        for (int df = 0; df < 8; df++) {
          bf16x8 vf = *(const bf16x8*)&V_[(df * 16 + l16) * 64 + ((kb2 * 32 + l4 * 8) ^ swz)];
          oacc[df] = __builtin_amdgcn_mfma_f32_16x16x32_bf16(vf, pf, oacc[df], 0, 0, 0);
        }
      }
    };

    stage(kt0, kt0 & 3);
    stage(kt0 + 1, (kt0 + 1) & 3);
    for (int tp = kt0; tp < nt; tp += 2) {
      if (tp + 2 < nt) {
        stage(tp + 2, (tp + 2) & 3);
        stage(tp + 3, (tp + 3) & 3);
        asm volatile("s_waitcnt vmcnt(8)" ::: "memory");   // tp, tp+1 landed
      } else {
        asm volatile("s_waitcnt vmcnt(0)" ::: "memory");
      }
      __builtin_amdgcn_sched_barrier(0);
      __builtin_amdgcn_s_barrier();                        // all waves see K/V
      tile(tp,     Kb[tp & 3],       Vb[tp & 3]);
      tile(tp + 1, Kb[(tp + 1) & 3], Vb[(tp + 1) & 3]);
      asm volatile("s_waitcnt lgkmcnt(0)" ::: "memory");   // LDS reads done
      __builtin_amdgcn_s_barrier();                        // before overwrite
    }

    lpart += __shfl_xor(lpart, 16, 64);
    lpart += __shfl_xor(lpart, 32, 64);
    const float linv = 1.f / lpart;
    const bf16* pgrow = qkvp + (size_t)(b * SEQ + iq) * 8192 + 6144 + h * 128;
    bf16* grow = gated + (size_t)(b * SEQ + iq) * 2048 + h * 128;
#pragma unroll
    for (int df = 0; df < 8; df++) {
      const int d0 = df * 16 + l4 * 4;
      bf16x4 pg4 = *(const bf16x4*)(pgrow + d0);
      bf16x4 o4;
#pragma unroll
      for (int r = 0; r < 4; r++) {
        float o  = oacc[df][r] * linv;
        float pg = (float)pg4[r];
        float silu = pg / (1.f + __expf(-pg));
        o4[r] = (bf16)(silu * o);
      }
      *(bf16x4*)(grow + d0) = o4;
    }
  };

  run_strip(15 - pr);    // long strip first
  run_strip(pr);         // short strip re-reads L2-warm K/V
}

// ---------------------------------------------------------------------------
extern "C" void kernel_launch(void* const* d_in, const int* in_sizes, int n_in,
                              void* d_out, int out_size, void* d_ws, size_t ws_size,
                              hipStream_t stream) {
  (void)in_sizes; (void)n_in; (void)out_size; (void)ws_size;
  const float* x      = (const float*)d_in[0];
  const float* w_in   = (const float*)d_in[1];
  const float* w_out  = (const float*)d_in[2];
  const float* lnig   = (const float*)d_in[3];
  const float* lnib   = (const float*)d_in[4];
  const float* lnog   = (const float*)d_in[5];
  const float* lnob   = (const float*)d_in[6];
  const float* slopes = (const float*)d_in[7];
  const float* smf    = (const float*)d_in[8];
  float* out = (float*)d_out;

  char* ws = (char*)d_ws;
  size_t off = 0;
  bf16* hb      = (bf16*)(ws + off); off += (size_t)4096 * 1024 * 2;  // h (bf16)
  bf16* w_in_b  = (bf16*)(ws + off); off += (size_t)8192 * 1024 * 2;
  bf16* w_out_b = (bf16*)(ws + off); off += (size_t)1024 * 2048 * 2;
  bf16* qkvp    = (bf16*)(ws + off); off += (size_t)4096 * 8192 * 2;
  bf16* ksm     = (bf16*)(ws + off); off += (size_t)32 * 2048 * 128 * 2;
  bf16* gated   = (bf16*)(ws + off); off += (size_t)4096 * 2048 * 2;
  float* yb0    = (float*)(ws + off); off += (size_t)4096 * 1024 * 4;
  float* yb1    = (float*)(ws + off); off += (size_t)4096 * 1024 * 4;
  bf16* vt      = (bf16*)yb0;  // alias: vt dead before gemm128 writes yb0

  prepass_kernel<<<9216, 256, 0, stream>>>(x, w_in, w_out, lnig, lnib,
                                           hb, w_in_b, w_out_b);
  gemm256<<<512, 1024, 0, stream>>>(hb, w_in_b, qkvp, 4096, 8192, 1024, 4, 8, 8);
  prep_kernel<<<dim3(32, 32), 256, 0, stream>>>(qkvp, smf, ksm, vt);
  attn_kernel<<<256, 512, 0, stream>>>(qkvp, ksm, vt, slopes, gated);
  gemm128<<<512, 256, 0, stream>>>(gated, w_out_b, yb0, 4096, 1024, 2048, 1, 8, 4);
  ln_kernel<<<4096, 256, 0, stream>>>(yb0, yb1, lnog, lnob, out);
}

// Round 19
// 202.376 us; speedup vs baseline: 1.0201x; 1.0201x over previous
//
#include <hip/hip_runtime.h>
#include <hip/hip_bf16.h>
#include <stdint.h>

// ---------------------------------------------------------------------------
// Block: LN -> [q,k,v,p] = h @ w_in^T -> key-smear -> causal attn w/ learned
// ALiBi -> o * silu(p) -> @ w_out^T -> LN.   B=2 L=2048 D=1024 H=16 Dh=128.
// Internal compute in bf16 MFMA.
// ---------------------------------------------------------------------------

typedef __bf16 bf16;
typedef bf16  bf16x8 __attribute__((ext_vector_type(8)));
typedef bf16  bf16x4 __attribute__((ext_vector_type(4)));
typedef float f32x4  __attribute__((ext_vector_type(4)));

#define SEQ   2048
#define NBATC 2

__device__ __forceinline__ void gld_lds16(const bf16* g, bf16* l) {
  __builtin_amdgcn_global_load_lds((const __attribute__((address_space(1))) void*)g,
                                   (__attribute__((address_space(3))) void*)l, 16, 0, 0);
}

// ---------------- device helpers -------------------------------------------
__device__ __forceinline__ void cvt8(const float* __restrict__ in,
                                     bf16* __restrict__ out, int t) {
  const float4* p = (const float4*)in + (size_t)t * 2;
  float4 a = p[0], b = p[1];
  bf16x8 o;
  o[0] = (bf16)a.x; o[1] = (bf16)a.y; o[2] = (bf16)a.z; o[3] = (bf16)a.w;
  o[4] = (bf16)b.x; o[5] = (bf16)b.y; o[6] = (bf16)b.z; o[7] = (bf16)b.w;
  *((bf16x8*)out + t) = o;
}

// ---------------- fused prepass: cvt(w_in) | cvt(w_out) | ln_in -------------
__global__ __launch_bounds__(256) void prepass_kernel(const float* __restrict__ x,
    const float* __restrict__ w_in, const float* __restrict__ w_out,
    const float* __restrict__ gamma, const float* __restrict__ beta,
    bf16* __restrict__ hb, bf16* __restrict__ w_in_b, bf16* __restrict__ w_out_b) {
  const int blk = blockIdx.x;
  const int tid = threadIdx.x;
  if (blk < 4096) {
    cvt8(w_in, w_in_b, blk * 256 + tid);
    return;
  }
  if (blk < 5120) {
    cvt8(w_out, w_out_b, (blk - 4096) * 256 + tid);
    return;
  }
  const int row = blk - 5120;
  float4 v = *(const float4*)(x + (size_t)row * 1024 + tid * 4);
  float s  = v.x + v.y + v.z + v.w;
  float ss = v.x * v.x + v.y * v.y + v.z * v.z + v.w * v.w;
#pragma unroll
  for (int m = 1; m < 64; m <<= 1) { s += __shfl_xor(s, m, 64); ss += __shfl_xor(ss, m, 64); }
  __shared__ float red[8];
  if ((tid & 63) == 0) { red[tid >> 6] = s; red[(tid >> 6) + 4] = ss; }
  __syncthreads();
  s  = red[0] + red[1] + red[2] + red[3];
  ss = red[4] + red[5] + red[6] + red[7];
  const float mu  = s * (1.f / 1024.f);
  const float inv = rsqrtf(ss * (1.f / 1024.f) - mu * mu + 1e-5f);
  float4 g  = *(const float4*)(gamma + tid * 4);
  float4 bb = *(const float4*)(beta  + tid * 4);
  bf16* o = hb + (size_t)row * 1024 + tid * 4;
  o[0] = (bf16)((v.x - mu) * inv * g.x + bb.x);
  o[1] = (bf16)((v.y - mu) * inv * g.y + bb.y);
  o[2] = (bf16)((v.z - mu) * inv * g.z + bb.z);
  o[3] = (bf16)((v.w - mu) * inv * g.w + bb.w);
}

// ---------------- final LayerNorm: sums split-K partials yb0+yb1 ------------
__global__ __launch_bounds__(256) void ln_kernel(const float* __restrict__ y0,
    const float* __restrict__ y1, const float* __restrict__ gamma,
    const float* __restrict__ beta, float* __restrict__ out) {
  const int row = blockIdx.x;
  const int tid = threadIdx.x;
  float4 a = *(const float4*)(y0 + (size_t)row * 1024 + tid * 4);
  float4 c = *(const float4*)(y1 + (size_t)row * 1024 + tid * 4);
  float4 v = {a.x + c.x, a.y + c.y, a.z + c.z, a.w + c.w};
  float s  = v.x + v.y + v.z + v.w;
  float ss = v.x * v.x + v.y * v.y + v.z * v.z + v.w * v.w;
#pragma unroll
  for (int m = 1; m < 64; m <<= 1) { s += __shfl_xor(s, m, 64); ss += __shfl_xor(ss, m, 64); }
  __shared__ float red[8];
  if ((tid & 63) == 0) { red[tid >> 6] = s; red[(tid >> 6) + 4] = ss; }
  __syncthreads();
  s  = red[0] + red[1] + red[2] + red[3];
  ss = red[4] + red[5] + red[6] + red[7];
  const float mu  = s * (1.f / 1024.f);
  const float inv = rsqrtf(ss * (1.f / 1024.f) - mu * mu + 1e-5f);
  float4 g  = *(const float4*)(gamma + tid * 4);
  float4 bb = *(const float4*)(beta  + tid * 4);
  float* o = out + (size_t)row * 1024 + tid * 4;
  o[0] = (v.x - mu) * inv * g.x + bb.x;
  o[1] = (v.y - mu) * inv * g.y + bb.y;
  o[2] = (v.z - mu) * inv * g.z + bb.z;
  o[3] = (v.w - mu) * inv * g.w + bb.w;
}

// ---------------- fused key-smear (XOR-swizzled ksm) + V transpose ----------
__global__ __launch_bounds__(256) void prep_kernel(const bf16* __restrict__ qkvp,
    const float* __restrict__ smf, bf16* __restrict__ ksm, bf16* __restrict__ vt) {
  __shared__ bf16 T[128][72];
  const int kt = blockIdx.x, bh = blockIdx.y;
  const int b = bh >> 4, h = bh & 15;
  const int t = threadIdx.x;

  {
    int i = t >> 2, d0 = (t & 3) * 32;
    const bf16* src = qkvp + (size_t)(b * SEQ + kt * 64 + i) * 8192 + 4096 + h * 128 + d0;
#pragma unroll
    for (int m = 0; m < 4; m++) {
      bf16x8 v8 = *(const bf16x8*)(src + m * 8);
#pragma unroll
      for (int e = 0; e < 8; e++) T[d0 + m * 8 + e][i] = v8[e];
    }
  }

  {
    float sm = 1.f / (1.f + __expf(-smf[h]));
#pragma unroll
    for (int j = 0; j < 4; j++) {
      int c  = j * 256 + t;
      int il = c >> 4, d8 = c & 15;
      int i  = kt * 64 + il;
      const bf16* base = qkvp + (size_t)(b * SEQ + i) * 8192 + 2048 + h * 128 + d8 * 8;
      bf16x8 cur = *(const bf16x8*)base;
      bf16x8 prv = cur;
      if (i > 0) prv = *(const bf16x8*)(base - 8192);
      bf16x8 o;
#pragma unroll
      for (int e = 0; e < 8; e++) {
        float pv = (i > 0) ? (float)prv[e] : 0.f;
        o[e] = (bf16)((1.f - sm) * (float)cur[e] + sm * pv);
      }
      size_t idx = ((size_t)bh * SEQ + i) * 128 + ((d8 * 8) ^ ((i & 7) << 3));
      *(bf16x8*)(ksm + idx) = o;
    }
  }

  __syncthreads();
  {
    int d = t >> 1, i0 = (t & 1) * 32;
    bf16* dst = vt + (size_t)bh * (SEQ * 128) + (size_t)kt * 8192 + d * 64;
#pragma unroll
    for (int m = 0; m < 4; m++) {
      bf16x8 v8 = *(const bf16x8*)&T[d][i0 + m * 8];
      *(bf16x8*)(dst + (((i0 + m * 8)) ^ ((d & 7) << 3))) = v8;
    }
  }
}

// ---------------- GEMM 256x256 tile, BK=64, 16 waves, counted-vmcnt ---------
// 256 blocks, TWO M-adjacent output tiles per block (by0, by0+4) sharing bx:
// single dispatch round, second tile's B panel L2-hot.  Inner K-loop is the
// r17-proven schedule: stage(t+1); vmcnt(4); barrier; ds_read+MFMA; lgkm(0);
// barrier.  XOR-swizzled LDS via pre-swizzled global source.
__global__ __launch_bounds__(1024, 4) void gemm256(const bf16* __restrict__ A,
    const bf16* __restrict__ Bt, bf16* __restrict__ C, int M, int N, int K,
    int RX, int SX, int SY) {
  __shared__ bf16 As[2][256 * 64];
  __shared__ bf16 Bs[2][256 * 64];
  const int w   = blockIdx.x;                     // 0..255
  const int xcd = w & 7, idx = w >> 3;            // idx 0..31
  const int rx = xcd % RX, ry = xcd / RX;
  const int bx  = rx * SX + (idx & 7);
  const int by0 = ry * SY + (idx >> 3);           // 0..3 within region
  const int tid  = threadIdx.x;
  const int lane = tid & 63, wid = tid >> 6;      // wid 0..15
  const int l4 = lane >> 4, l16 = lane & 15;
  const int wr = wid >> 2, wc = wid & 3;          // 4 x 4 waves
  const int colBase = bx * 256;
  const int NT = K >> 6;

  for (int half = 0; half < 2; ++half) {
    const int rowBase = (by0 + half * 4) * 256;

    f32x4 acc[4][4];
    const f32x4 z = {0.f, 0.f, 0.f, 0.f};
#pragma unroll
    for (int i = 0; i < 4; i++)
#pragma unroll
      for (int j = 0; j < 4; j++) acc[i][j] = z;

    auto stage = [&](int t_, int buf) {   // 4 gld_lds per thread
      const int k0 = t_ * 64;
#pragma unroll
      for (int j = 0; j < 2; ++j) {
        const int c   = j * 1024 + tid;   // 2048 16B-chunks per array
        const int row = c >> 3;           // 0..255
        const int sc  = ((c & 7) * 8) ^ ((row & 7) << 3);   // pre-swizzled col
        gld_lds16(A  + (size_t)(rowBase + row) * K + k0 + sc, &As[buf][c * 8]);
        gld_lds16(Bt + (size_t)(colBase + row) * K + k0 + sc, &Bs[buf][c * 8]);
      }
    };

    stage(0, 0);
    for (int t = 0; t < NT; ++t) {
      const int cur = t & 1;
      if (t + 1 < NT) {
        stage(t + 1, cur ^ 1);                             // 4 loads in flight
        asm volatile("s_waitcnt vmcnt(4)" ::: "memory");   // tile t landed
      } else {
        asm volatile("s_waitcnt vmcnt(0)" ::: "memory");
      }
      __builtin_amdgcn_sched_barrier(0);
      __builtin_amdgcn_s_barrier();
      const bf16* a_ = &As[cur][0];
      const bf16* b_ = &Bs[cur][0];
#pragma unroll
      for (int ks = 0; ks < 2; ++ks) {
        bf16x8 bfr[4];
#pragma unroll
        for (int ni = 0; ni < 4; ++ni) {
          const int br = wc * 64 + ni * 16 + l16;
          bfr[ni] = *(const bf16x8*)&b_[br * 64 + ((ks * 32 + l4 * 8) ^ ((br & 7) << 3))];
        }
#pragma unroll
        for (int mi = 0; mi < 4; ++mi) {
          const int ar = wr * 64 + mi * 16 + l16;
          bf16x8 af = *(const bf16x8*)&a_[ar * 64 + ((ks * 32 + l4 * 8) ^ ((ar & 7) << 3))];
#pragma unroll
          for (int ni = 0; ni < 4; ++ni)
            acc[mi][ni] = __builtin_amdgcn_mfma_f32_16x16x32_bf16(af, bfr[ni], acc[mi][ni], 0, 0, 0);
        }
      }
      asm volatile("s_waitcnt lgkmcnt(0)" ::: "memory");   // LDS reads done
      __builtin_amdgcn_s_barrier();                        // before overwrite
    }

#pragma unroll
    for (int mi = 0; mi < 4; ++mi)
#pragma unroll
      for (int ni = 0; ni < 4; ++ni) {
        int row = rowBase + wr * 64 + mi * 16 + l4 * 4;
        int col = colBase + wc * 64 + ni * 16 + l16;
#pragma unroll
        for (int r = 0; r < 4; ++r)
          C[(size_t)(row + r) * N + col] = (bf16)acc[mi][ni][r];
      }
  }
}

// ---------------- GEMM 128x128 tile, BK=64, split-K=2 (for gemm2) -----------
__global__ __launch_bounds__(256, 2) void gemm128(const bf16* __restrict__ A,
    const bf16* __restrict__ Bt, float* __restrict__ C, int M, int N, int K,
    int RX, int SX, int SY) {
  __shared__ bf16 As[2][128 * 64];
  __shared__ bf16 Bs[2][128 * 64];
  const int w   = blockIdx.x & 255;
  const int ksl = blockIdx.x >> 8;         // K-slice 0/1
  const int xcd = w & 7, idx = w >> 3;
  const int rx = xcd % RX, ry = xcd / RX;
  const int bx = rx * SX + idx % SX;
  const int by = ry * SY + idx / SX;
  const int tid  = threadIdx.x;
  const int lane = tid & 63, wid = tid >> 6;
  const int l4 = lane >> 4, l16 = lane & 15;
  const int wr = wid >> 1, wc = wid & 1;
  const int rowBase = by * 128, colBase = bx * 128;
  const int KH = K >> 1;                   // 1024
  const int kbase = ksl * KH;
  const int NT = KH >> 6;                  // 16
  float* Cp = C + (size_t)ksl * M * N;

  f32x4 acc[4][4];
  const f32x4 z = {0.f, 0.f, 0.f, 0.f};
#pragma unroll
  for (int i = 0; i < 4; i++)
#pragma unroll
    for (int j = 0; j < 4; j++) acc[i][j] = z;

  auto stage = [&](int t_, int buf) {      // 8 gld_lds per thread
    const int k0 = kbase + t_ * 64;
#pragma unroll
    for (int j = 0; j < 4; ++j) {
      const int c   = j * 256 + tid;       // 1024 chunks of 16B per array
      const int row = c >> 3;              // 0..127
      const int sc  = ((c & 7) * 8) ^ ((row & 7) << 3);
      gld_lds16(A  + (size_t)(rowBase + row) * K + k0 + sc, &As[buf][c * 8]);
      gld_lds16(Bt + (size_t)(colBase + row) * K + k0 + sc, &Bs[buf][c * 8]);
    }
  };

  stage(0, 0);
  for (int t = 0; t < NT; ++t) {
    const int cur = t & 1;
    if (t + 1 < NT) {
      stage(t + 1, cur ^ 1);
      asm volatile("s_waitcnt vmcnt(8)" ::: "memory");   // tile t landed
    } else {
      asm volatile("s_waitcnt vmcnt(0)" ::: "memory");
    }
    __builtin_amdgcn_sched_barrier(0);
    __builtin_amdgcn_s_barrier();
    const bf16* a_ = &As[cur][0];
    const bf16* b_ = &Bs[cur][0];
#pragma unroll
    for (int ks = 0; ks < 2; ++ks) {
      bf16x8 bfr[4];
#pragma unroll
      for (int ni = 0; ni < 4; ++ni) {
        const int br = wc * 64 + ni * 16 + l16;
        bfr[ni] = *(const bf16x8*)&b_[br * 64 + ((ks * 32 + l4 * 8) ^ ((br & 7) << 3))];
      }
#pragma unroll
      for (int mi = 0; mi < 4; ++mi) {
        const int ar = wr * 64 + mi * 16 + l16;
        bf16x8 af = *(const bf16x8*)&a_[ar * 64 + ((ks * 32 + l4 * 8) ^ ((ar & 7) << 3))];
#pragma unroll
        for (int ni = 0; ni < 4; ++ni)
          acc[mi][ni] = __builtin_amdgcn_mfma_f32_16x16x32_bf16(af, bfr[ni], acc[mi][ni], 0, 0, 0);
      }
    }
    asm volatile("s_waitcnt lgkmcnt(0)" ::: "memory");
    __builtin_amdgcn_s_barrier();
  }

#pragma unroll
  for (int mi = 0; mi < 4; ++mi)
#pragma unroll
    for (int ni = 0; ni < 4; ++ni) {
      int row = rowBase + wr * 64 + mi * 16 + l4 * 4;
      int col = colBase + wc * 64 + ni * 16 + l16;
#pragma unroll
      for (int r = 0; r < 4; ++r)
        Cp[(size_t)(row + r) * N + col] = acc[mi][ni][r];
    }
}

// ---------------- flash attention + ALiBi + causal + silu-gate --------------
// [round-13 proven: 78.8us — DO NOT RESTRUCTURE]  256 blocks = 1/CU.
// Block = (bh, pair p): strips qt=15-p then qt=p.  4-buffer LDS ring, TWO
// tiles per barrier pair, counted vmcnt(8).  Swapped-QK^T.  ALiBi window skip.
__global__ __launch_bounds__(512, 2) void attn_kernel(const bf16* __restrict__ qkvp,
    const bf16* __restrict__ ksm, const bf16* __restrict__ vt,
    const float* __restrict__ slopes, bf16* __restrict__ gated) {
  const int w   = blockIdx.x;              // 256 = 8 xcd * 4 bh * 8 pairs
  const int xcd = w & 7;
  const int bh  = xcd * 4 + ((w >> 3) & 3);
  const int pr  = w >> 5;                  // 0..7
  const int b   = bh >> 4, h = bh & 15;
  const int tid = threadIdx.x, wid = tid >> 6, lane = tid & 63;
  const int l4 = lane >> 4, l16 = lane & 15;
  const int swz = (l16 & 7) << 3;
  const float LOG2E = 1.44269504f;
  const float s2 = 0.08838834764831845f * LOG2E;   // (1/sqrt(128))*log2e
  const float slopeL = slopes[h] * LOG2E;

  __shared__ bf16 Kb[4][64 * 128];
  __shared__ bf16 Vb[4][64 * 128];
  __shared__ bf16 P_lds[128 * 64];  // [qrow(128)][k ^ ((qrow&7)<<3)], wave-priv

  const bf16* ksmB = ksm + (size_t)bh * SEQ * 128;
  const bf16* vtB  = vt  + (size_t)bh * SEQ * 128;

  auto stage = [&](int kt, int bsel) {     // 4 loads/thread
#pragma unroll
    for (int j = 0; j < 2; j++) {
      const int c = j * 512 + tid;         // 1024 chunks of 16B
      gld_lds16(ksmB + (size_t)kt * 8192 + c * 8, &Kb[bsel][c * 8]);
      gld_lds16(vtB  + (size_t)kt * 8192 + c * 8, &Vb[bsel][c * 8]);
    }
  };

  auto run_strip = [&](int qtile) {
    const int nt = 2 * qtile + 2;
    int kt0 = 0;
    if (slopeL > 1e-6f) {
      const int W = (int)(64.f / slopeL + 128.f);
      const int wlim = qtile * 128 - W - 63;
      if (wlim > 0) kt0 = (wlim >> 6) & ~1;      // even, >= 0, < nt
    }
    const int iq = qtile * 128 + wid * 16 + l16;   // this lane's q-row
    bf16x8 qf[4];
    {
      const bf16* qrow = qkvp + (size_t)(b * SEQ + iq) * 8192 + h * 128;
#pragma unroll
      for (int kb = 0; kb < 4; kb++) qf[kb] = *(const bf16x8*)(qrow + kb * 32 + l4 * 8);
    }
    f32x4 oacc[8];   // oacc[df][r] = O[iq][df*16 + l4*4 + r]
    const f32x4 z = {0.f, 0.f, 0.f, 0.f};
#pragma unroll
    for (int i = 0; i < 8; i++) oacc[i] = z;
    float m2 = -1e38f, lpart = 0.f;

    auto tile = [&](int t, const bf16* K_, const bf16* V_) {
      f32x4 sacc[4];
#pragma unroll
      for (int jf = 0; jf < 4; jf++) {
        f32x4 a = z;
#pragma unroll
        for (int kb = 0; kb < 4; kb++) {
          bf16x8 kf = *(const bf16x8*)&K_[(jf * 16 + l16) * 128 + ((kb * 32 + l4 * 8) ^ swz)];
          a = __builtin_amdgcn_mfma_f32_16x16x32_bf16(kf, qf[kb], a, 0, 0, 0);
        }
        sacc[jf] = a;
      }

      const bool diag = (t >= 2 * qtile);
      const int kbase = t * 64 + l4 * 4;
#pragma unroll
      for (int jf = 0; jf < 4; jf++) {
#pragma unroll
        for (int r = 0; r < 4; r++) {
          int j = kbase + jf * 16 + r;
          float v = fmaf(sacc[jf][r], s2, (float)j * slopeL);
          if (diag && j > iq) v = -1e38f;
          sacc[jf][r] = v;
        }
      }

      float mx = sacc[0][0];
#pragma unroll
      for (int jf = 0; jf < 4; jf++)
#pragma unroll
        for (int r = 0; r < 4; r++) mx = fmaxf(mx, sacc[jf][r]);
      mx = fmaxf(mx, __shfl_xor(mx, 16, 64));
      mx = fmaxf(mx, __shfl_xor(mx, 32, 64));

      if (__any(mx > m2 + 14.f)) {         // uniform defer-max rescale
        float mnew  = fmaxf(m2, mx);
        float alpha = __builtin_amdgcn_exp2f(m2 - mnew);
        m2 = mnew;
        lpart *= alpha;
#pragma unroll
        for (int df = 0; df < 8; df++) oacc[df] *= alpha;
      }

      float rs = 0.f;
#pragma unroll
      for (int jf = 0; jf < 4; jf++) {
        bf16x4 pw;
#pragma unroll
        for (int r = 0; r < 4; r++) {
          float pe = __builtin_amdgcn_exp2f(sacc[jf][r] - m2);
          rs += pe;
          pw[r] = (bf16)pe;
        }
        *(bf16x4*)&P_lds[(wid * 16 + l16) * 64 + ((jf * 16 + l4 * 4) ^ swz)] = pw;
      }
      lpart += rs;

#pragma unroll
      for (int kb2 = 0; kb2 < 2; ++kb2) {
        bf16x8 pf = *(const bf16x8*)&P_lds[(wid * 16 + l16) * 64 + ((kb2 * 32 + l4 * 8) ^ swz)];
#pragma unroll
        for (int df = 0; df < 8; df++) {
          bf16x8 vf = *(const bf16x8*)&V_[(df * 16 + l16) * 64 + ((kb2 * 32 + l4 * 8) ^ swz)];
          oacc[df] = __builtin_amdgcn_mfma_f32_16x16x32_bf16(vf, pf, oacc[df], 0, 0, 0);
        }
      }
    };

    stage(kt0, kt0 & 3);
    stage(kt0 + 1, (kt0 + 1) & 3);
    for (int tp = kt0; tp < nt; tp += 2) {
      if (tp + 2 < nt) {
        stage(tp + 2, (tp + 2) & 3);
        stage(tp + 3, (tp + 3) & 3);
        asm volatile("s_waitcnt vmcnt(8)" ::: "memory");   // tp, tp+1 landed
      } else {
        asm volatile("s_waitcnt vmcnt(0)" ::: "memory");
      }
      __builtin_amdgcn_sched_barrier(0);
      __builtin_amdgcn_s_barrier();                        // all waves see K/V
      tile(tp,     Kb[tp & 3],       Vb[tp & 3]);
      tile(tp + 1, Kb[(tp + 1) & 3], Vb[(tp + 1) & 3]);
      asm volatile("s_waitcnt lgkmcnt(0)" ::: "memory");   // LDS reads done
      __builtin_amdgcn_s_barrier();                        // before overwrite
    }

    lpart += __shfl_xor(lpart, 16, 64);
    lpart += __shfl_xor(lpart, 32, 64);
    const float linv = 1.f / lpart;
    const bf16* pgrow = qkvp + (size_t)(b * SEQ + iq) * 8192 + 6144 + h * 128;
    bf16* grow = gated + (size_t)(b * SEQ + iq) * 2048 + h * 128;
#pragma unroll
    for (int df = 0; df < 8; df++) {
      const int d0 = df * 16 + l4 * 4;
      bf16x4 pg4 = *(const bf16x4*)(pgrow + d0);
      bf16x4 o4;
#pragma unroll
      for (int r = 0; r < 4; r++) {
        float o  = oacc[df][r] * linv;
        float pg = (float)pg4[r];
        float silu = pg / (1.f + __expf(-pg));
        o4[r] = (bf16)(silu * o);
      }
      *(bf16x4*)(grow + d0) = o4;
    }
  };

  run_strip(15 - pr);    // long strip first
  run_strip(pr);         // short strip re-reads L2-warm K/V
}

// ---------------------------------------------------------------------------
extern "C" void kernel_launch(void* const* d_in, const int* in_sizes, int n_in,
                              void* d_out, int out_size, void* d_ws, size_t ws_size,
                              hipStream_t stream) {
  (void)in_sizes; (void)n_in; (void)out_size; (void)ws_size;
  const float* x      = (const float*)d_in[0];
  const float* w_in   = (const float*)d_in[1];
  const float* w_out  = (const float*)d_in[2];
  const float* lnig   = (const float*)d_in[3];
  const float* lnib   = (const float*)d_in[4];
  const float* lnog   = (const float*)d_in[5];
  const float* lnob   = (const float*)d_in[6];
  const float* slopes = (const float*)d_in[7];
  const float* smf    = (const float*)d_in[8];
  float* out = (float*)d_out;

  char* ws = (char*)d_ws;
  size_t off = 0;
  bf16* hb      = (bf16*)(ws + off); off += (size_t)4096 * 1024 * 2;  // h (bf16)
  bf16* w_in_b  = (bf16*)(ws + off); off += (size_t)8192 * 1024 * 2;
  bf16* w_out_b = (bf16*)(ws + off); off += (size_t)1024 * 2048 * 2;
  bf16* qkvp    = (bf16*)(ws + off); off += (size_t)4096 * 8192 * 2;
  bf16* ksm     = (bf16*)(ws + off); off += (size_t)32 * 2048 * 128 * 2;
  bf16* gated   = (bf16*)(ws + off); off += (size_t)4096 * 2048 * 2;
  float* yb0    = (float*)(ws + off); off += (size_t)4096 * 1024 * 4;
  float* yb1    = (float*)(ws + off); off += (size_t)4096 * 1024 * 4;
  bf16* vt      = (bf16*)yb0;  // alias: vt dead before gemm128 writes yb0

  prepass_kernel<<<9216, 256, 0, stream>>>(x, w_in, w_out, lnig, lnib,
                                           hb, w_in_b, w_out_b);
  gemm256<<<256, 1024, 0, stream>>>(hb, w_in_b, qkvp, 4096, 8192, 1024, 4, 8, 8);
  prep_kernel<<<dim3(32, 32), 256, 0, stream>>>(qkvp, smf, ksm, vt);
  attn_kernel<<<256, 512, 0, stream>>>(qkvp, ksm, vt, slopes, gated);
  gemm128<<<512, 256, 0, stream>>>(gated, w_out_b, yb0, 4096, 1024, 2048, 1, 8, 4);
  ln_kernel<<<4096, 256, 0, stream>>>(yb0, yb1, lnog, lnob, out);
}

// Round 20
// 199.490 us; speedup vs baseline: 1.0349x; 1.0145x over previous
//
#include <hip/hip_runtime.h>
#include <hip/hip_bf16.h>
#include <stdint.h>

// ---------------------------------------------------------------------------
// Block: LN -> [q,k,v,p] = h @ w_in^T -> key-smear -> causal attn w/ learned
// ALiBi -> o * silu(p) -> @ w_out^T -> LN.   B=2 L=2048 D=1024 H=16 Dh=128.
// Internal compute in bf16 MFMA.
// ---------------------------------------------------------------------------

typedef __bf16 bf16;
typedef bf16  bf16x8 __attribute__((ext_vector_type(8)));
typedef bf16  bf16x4 __attribute__((ext_vector_type(4)));
typedef float f32x4  __attribute__((ext_vector_type(4)));

#define SEQ   2048
#define NBATC 2

__device__ __forceinline__ void gld_lds16(const bf16* g, bf16* l) {
  __builtin_amdgcn_global_load_lds((const __attribute__((address_space(1))) void*)g,
                                   (__attribute__((address_space(3))) void*)l, 16, 0, 0);
}

// ---------------- device helpers -------------------------------------------
__device__ __forceinline__ void cvt8(const float* __restrict__ in,
                                     bf16* __restrict__ out, int t) {
  const float4* p = (const float4*)in + (size_t)t * 2;
  float4 a = p[0], b = p[1];
  bf16x8 o;
  o[0] = (bf16)a.x; o[1] = (bf16)a.y; o[2] = (bf16)a.z; o[3] = (bf16)a.w;
  o[4] = (bf16)b.x; o[5] = (bf16)b.y; o[6] = (bf16)b.z; o[7] = (bf16)b.w;
  *((bf16x8*)out + t) = o;
}

// ---------------- fused prepass: cvt(w_in) | cvt(w_out) | ln_in -------------
__global__ __launch_bounds__(256) void prepass_kernel(const float* __restrict__ x,
    const float* __restrict__ w_in, const float* __restrict__ w_out,
    const float* __restrict__ gamma, const float* __restrict__ beta,
    bf16* __restrict__ hb, bf16* __restrict__ w_in_b, bf16* __restrict__ w_out_b) {
  const int blk = blockIdx.x;
  const int tid = threadIdx.x;
  if (blk < 4096) {
    cvt8(w_in, w_in_b, blk * 256 + tid);
    return;
  }
  if (blk < 5120) {
    cvt8(w_out, w_out_b, (blk - 4096) * 256 + tid);
    return;
  }
  const int row = blk - 5120;
  float4 v = *(const float4*)(x + (size_t)row * 1024 + tid * 4);
  float s  = v.x + v.y + v.z + v.w;
  float ss = v.x * v.x + v.y * v.y + v.z * v.z + v.w * v.w;
#pragma unroll
  for (int m = 1; m < 64; m <<= 1) { s += __shfl_xor(s, m, 64); ss += __shfl_xor(ss, m, 64); }
  __shared__ float red[8];
  if ((tid & 63) == 0) { red[tid >> 6] = s; red[(tid >> 6) + 4] = ss; }
  __syncthreads();
  s  = red[0] + red[1] + red[2] + red[3];
  ss = red[4] + red[5] + red[6] + red[7];
  const float mu  = s * (1.f / 1024.f);
  const float inv = rsqrtf(ss * (1.f / 1024.f) - mu * mu + 1e-5f);
  float4 g  = *(const float4*)(gamma + tid * 4);
  float4 bb = *(const float4*)(beta  + tid * 4);
  bf16* o = hb + (size_t)row * 1024 + tid * 4;
  o[0] = (bf16)((v.x - mu) * inv * g.x + bb.x);
  o[1] = (bf16)((v.y - mu) * inv * g.y + bb.y);
  o[2] = (bf16)((v.z - mu) * inv * g.z + bb.z);
  o[3] = (bf16)((v.w - mu) * inv * g.w + bb.w);
}

// ---------------- final LayerNorm: sums bf16 split-K partials y0+y1 ---------
__global__ __launch_bounds__(256) void ln_kernel(const bf16* __restrict__ y0,
    const bf16* __restrict__ y1, const float* __restrict__ gamma,
    const float* __restrict__ beta, float* __restrict__ out) {
  const int row = blockIdx.x;
  const int tid = threadIdx.x;
  bf16x4 a4 = *(const bf16x4*)(y0 + (size_t)row * 1024 + tid * 4);
  bf16x4 c4 = *(const bf16x4*)(y1 + (size_t)row * 1024 + tid * 4);
  float4 v = {(float)a4[0] + (float)c4[0], (float)a4[1] + (float)c4[1],
              (float)a4[2] + (float)c4[2], (float)a4[3] + (float)c4[3]};
  float s  = v.x + v.y + v.z + v.w;
  float ss = v.x * v.x + v.y * v.y + v.z * v.z + v.w * v.w;
#pragma unroll
  for (int m = 1; m < 64; m <<= 1) { s += __shfl_xor(s, m, 64); ss += __shfl_xor(ss, m, 64); }
  __shared__ float red[8];
  if ((tid & 63) == 0) { red[tid >> 6] = s; red[(tid >> 6) + 4] = ss; }
  __syncthreads();
  s  = red[0] + red[1] + red[2] + red[3];
  ss = red[4] + red[5] + red[6] + red[7];
  const float mu  = s * (1.f / 1024.f);
  const float inv = rsqrtf(ss * (1.f / 1024.f) - mu * mu + 1e-5f);
  float4 g  = *(const float4*)(gamma + tid * 4);
  float4 bb = *(const float4*)(beta  + tid * 4);
  float* o = out + (size_t)row * 1024 + tid * 4;
  o[0] = (v.x - mu) * inv * g.x + bb.x;
  o[1] = (v.y - mu) * inv * g.y + bb.y;
  o[2] = (v.z - mu) * inv * g.z + bb.z;
  o[3] = (v.w - mu) * inv * g.w + bb.w;
}

// ---------------- fused key-smear (XOR-swizzled ksm) + V transpose ----------
__global__ __launch_bounds__(256) void prep_kernel(const bf16* __restrict__ qkvp,
    const float* __restrict__ smf, bf16* __restrict__ ksm, bf16* __restrict__ vt) {
  __shared__ bf16 T[128][72];
  const int kt = blockIdx.x, bh = blockIdx.y;
  const int b = bh >> 4, h = bh & 15;
  const int t = threadIdx.x;

  {
    int i = t >> 2, d0 = (t & 3) * 32;
    const bf16* src = qkvp + (size_t)(b * SEQ + kt * 64 + i) * 8192 + 4096 + h * 128 + d0;
#pragma unroll
    for (int m = 0; m < 4; m++) {
      bf16x8 v8 = *(const bf16x8*)(src + m * 8);
#pragma unroll
      for (int e = 0; e < 8; e++) T[d0 + m * 8 + e][i] = v8[e];
    }
  }

  {
    float sm = 1.f / (1.f + __expf(-smf[h]));
#pragma unroll
    for (int j = 0; j < 4; j++) {
      int c  = j * 256 + t;
      int il = c >> 4, d8 = c & 15;
      int i  = kt * 64 + il;
      const bf16* base = qkvp + (size_t)(b * SEQ + i) * 8192 + 2048 + h * 128 + d8 * 8;
      bf16x8 cur = *(const bf16x8*)base;
      bf16x8 prv = cur;
      if (i > 0) prv = *(const bf16x8*)(base - 8192);
      bf16x8 o;
#pragma unroll
      for (int e = 0; e < 8; e++) {
        float pv = (i > 0) ? (float)prv[e] : 0.f;
        o[e] = (bf16)((1.f - sm) * (float)cur[e] + sm * pv);
      }
      size_t idx = ((size_t)bh * SEQ + i) * 128 + ((d8 * 8) ^ ((i & 7) << 3));
      *(bf16x8*)(ksm + idx) = o;
    }
  }

  __syncthreads();
  {
    int d = t >> 1, i0 = (t & 1) * 32;
    bf16* dst = vt + (size_t)bh * (SEQ * 128) + (size_t)kt * 8192 + d * 64;
#pragma unroll
    for (int m = 0; m < 4; m++) {
      bf16x8 v8 = *(const bf16x8*)&T[d][i0 + m * 8];
      *(bf16x8*)(dst + (((i0 + m * 8)) ^ ((d & 7) << 3))) = v8;
    }
  }
}

// ---------------- GEMM 256x256 tile, BK=64, 16 waves, counted-vmcnt ---------
// 256 blocks, TWO M-adjacent output tiles per block sharing bx.
__global__ __launch_bounds__(1024, 4) void gemm256(const bf16* __restrict__ A,
    const bf16* __restrict__ Bt, bf16* __restrict__ C, int M, int N, int K,
    int RX, int SX, int SY) {
  __shared__ bf16 As[2][256 * 64];
  __shared__ bf16 Bs[2][256 * 64];
  const int w   = blockIdx.x;                     // 0..255
  const int xcd = w & 7, idx = w >> 3;            // idx 0..31
  const int rx = xcd % RX, ry = xcd / RX;
  const int bx  = rx * SX + (idx & 7);
  const int by0 = ry * SY + (idx >> 3);           // 0..3 within region
  const int tid  = threadIdx.x;
  const int lane = tid & 63, wid = tid >> 6;      // wid 0..15
  const int l4 = lane >> 4, l16 = lane & 15;
  const int wr = wid >> 2, wc = wid & 3;          // 4 x 4 waves
  const int colBase = bx * 256;
  const int NT = K >> 6;

  for (int half = 0; half < 2; ++half) {
    const int rowBase = (by0 + half * 4) * 256;

    f32x4 acc[4][4];
    const f32x4 z = {0.f, 0.f, 0.f, 0.f};
#pragma unroll
    for (int i = 0; i < 4; i++)
#pragma unroll
      for (int j = 0; j < 4; j++) acc[i][j] = z;

    auto stage = [&](int t_, int buf) {   // 4 gld_lds per thread
      const int k0 = t_ * 64;
#pragma unroll
      for (int j = 0; j < 2; ++j) {
        const int c   = j * 1024 + tid;   // 2048 16B-chunks per array
        const int row = c >> 3;           // 0..255
        const int sc  = ((c & 7) * 8) ^ ((row & 7) << 3);   // pre-swizzled col
        gld_lds16(A  + (size_t)(rowBase + row) * K + k0 + sc, &As[buf][c * 8]);
        gld_lds16(Bt + (size_t)(colBase + row) * K + k0 + sc, &Bs[buf][c * 8]);
      }
    };

    stage(0, 0);
    for (int t = 0; t < NT; ++t) {
      const int cur = t & 1;
      if (t + 1 < NT) {
        stage(t + 1, cur ^ 1);                             // 4 loads in flight
        asm volatile("s_waitcnt vmcnt(4)" ::: "memory");   // tile t landed
      } else {
        asm volatile("s_waitcnt vmcnt(0)" ::: "memory");
      }
      __builtin_amdgcn_sched_barrier(0);
      __builtin_amdgcn_s_barrier();
      const bf16* a_ = &As[cur][0];
      const bf16* b_ = &Bs[cur][0];
#pragma unroll
      for (int ks = 0; ks < 2; ++ks) {
        bf16x8 bfr[4];
#pragma unroll
        for (int ni = 0; ni < 4; ++ni) {
          const int br = wc * 64 + ni * 16 + l16;
          bfr[ni] = *(const bf16x8*)&b_[br * 64 + ((ks * 32 + l4 * 8) ^ ((br & 7) << 3))];
        }
#pragma unroll
        for (int mi = 0; mi < 4; ++mi) {
          const int ar = wr * 64 + mi * 16 + l16;
          bf16x8 af = *(const bf16x8*)&a_[ar * 64 + ((ks * 32 + l4 * 8) ^ ((ar & 7) << 3))];
#pragma unroll
          for (int ni = 0; ni < 4; ++ni)
            acc[mi][ni] = __builtin_amdgcn_mfma_f32_16x16x32_bf16(af, bfr[ni], acc[mi][ni], 0, 0, 0);
        }
      }
      asm volatile("s_waitcnt lgkmcnt(0)" ::: "memory");   // LDS reads done
      __builtin_amdgcn_s_barrier();                        // before overwrite
    }

#pragma unroll
    for (int mi = 0; mi < 4; ++mi)
#pragma unroll
      for (int ni = 0; ni < 4; ++ni) {
        int row = rowBase + wr * 64 + mi * 16 + l4 * 4;
        int col = colBase + wc * 64 + ni * 16 + l16;
#pragma unroll
        for (int r = 0; r < 4; ++r)
          C[(size_t)(row + r) * N + col] = (bf16)acc[mi][ni][r];
      }
  }
}

// ---------------- GEMM 128x128 tile, BK=64, split-K=2, bf16 partial out -----
__global__ __launch_bounds__(256, 2) void gemm128(const bf16* __restrict__ A,
    const bf16* __restrict__ Bt, bf16* __restrict__ C, int M, int N, int K,
    int RX, int SX, int SY) {
  __shared__ bf16 As[2][128 * 64];
  __shared__ bf16 Bs[2][128 * 64];
  const int w   = blockIdx.x & 255;
  const int ksl = blockIdx.x >> 8;         // K-slice 0/1
  const int xcd = w & 7, idx = w >> 3;
  const int rx = xcd % RX, ry = xcd / RX;
  const int bx = rx * SX + idx % SX;
  const int by = ry * SY + idx / SX;
  const int tid  = threadIdx.x;
  const int lane = tid & 63, wid = tid >> 6;
  const int l4 = lane >> 4, l16 = lane & 15;
  const int wr = wid >> 1, wc = wid & 1;
  const int rowBase = by * 128, colBase = bx * 128;
  const int KH = K >> 1;                   // 1024
  const int kbase = ksl * KH;
  const int NT = KH >> 6;                  // 16
  bf16* Cp = C + (size_t)ksl * M * N;

  f32x4 acc[4][4];
  const f32x4 z = {0.f, 0.f, 0.f, 0.f};
#pragma unroll
  for (int i = 0; i < 4; i++)
#pragma unroll
    for (int j = 0; j < 4; j++) acc[i][j] = z;

  auto stage = [&](int t_, int buf) {      // 8 gld_lds per thread
    const int k0 = kbase + t_ * 64;
#pragma unroll
    for (int j = 0; j < 4; ++j) {
      const int c   = j * 256 + tid;       // 1024 chunks of 16B per array
      const int row = c >> 3;              // 0..127
      const int sc  = ((c & 7) * 8) ^ ((row & 7) << 3);
      gld_lds16(A  + (size_t)(rowBase + row) * K + k0 + sc, &As[buf][c * 8]);
      gld_lds16(Bt + (size_t)(colBase + row) * K + k0 + sc, &Bs[buf][c * 8]);
    }
  };

  stage(0, 0);
  for (int t = 0; t < NT; ++t) {
    const int cur = t & 1;
    if (t + 1 < NT) {
      stage(t + 1, cur ^ 1);
      asm volatile("s_waitcnt vmcnt(8)" ::: "memory");   // tile t landed
    } else {
      asm volatile("s_waitcnt vmcnt(0)" ::: "memory");
    }
    __builtin_amdgcn_sched_barrier(0);
    __builtin_amdgcn_s_barrier();
    const bf16* a_ = &As[cur][0];
    const bf16* b_ = &Bs[cur][0];
#pragma unroll
    for (int ks = 0; ks < 2; ++ks) {
      bf16x8 bfr[4];
#pragma unroll
      for (int ni = 0; ni < 4; ++ni) {
        const int br = wc * 64 + ni * 16 + l16;
        bfr[ni] = *(const bf16x8*)&b_[br * 64 + ((ks * 32 + l4 * 8) ^ ((br & 7) << 3))];
      }
#pragma unroll
      for (int mi = 0; mi < 4; ++mi) {
        const int ar = wr * 64 + mi * 16 + l16;
        bf16x8 af = *(const bf16x8*)&a_[ar * 64 + ((ks * 32 + l4 * 8) ^ ((ar & 7) << 3))];
#pragma unroll
        for (int ni = 0; ni < 4; ++ni)
          acc[mi][ni] = __builtin_amdgcn_mfma_f32_16x16x32_bf16(af, bfr[ni], acc[mi][ni], 0, 0, 0);
      }
    }
    asm volatile("s_waitcnt lgkmcnt(0)" ::: "memory");
    __builtin_amdgcn_s_barrier();
  }

#pragma unroll
  for (int mi = 0; mi < 4; ++mi)
#pragma unroll
    for (int ni = 0; ni < 4; ++ni) {
      int row = rowBase + wr * 64 + mi * 16 + l4 * 4;
      int col = colBase + wc * 64 + ni * 16 + l16;
#pragma unroll
      for (int r = 0; r < 4; ++r)
        Cp[(size_t)(row + r) * N + col] = (bf16)acc[mi][ni][r];
    }
}

// ---------------- flash attention + ALiBi + causal + silu-gate --------------
// [round-13 proven: 78.8us — DO NOT RESTRUCTURE]  256 blocks = 1/CU.
// Block = (bh, pair p): strips qt=15-p then qt=p.  4-buffer LDS ring, TWO
// tiles per barrier pair, counted vmcnt(8).  Swapped-QK^T.  ALiBi window skip.
__global__ __launch_bounds__(512, 2) void attn_kernel(const bf16* __restrict__ qkvp,
    const bf16* __restrict__ ksm, const bf16* __restrict__ vt,
    const float* __restrict__ slopes, bf16* __restrict__ gated) {
  const int w   = blockIdx.x;              // 256 = 8 xcd * 4 bh * 8 pairs
  const int xcd = w & 7;
  const int bh  = xcd * 4 + ((w >> 3) & 3);
  const int pr  = w >> 5;                  // 0..7
  const int b   = bh >> 4, h = bh & 15;
  const int tid = threadIdx.x, wid = tid >> 6, lane = tid & 63;
  const int l4 = lane >> 4, l16 = lane & 15;
  const int swz = (l16 & 7) << 3;
  const float LOG2E = 1.44269504f;
  const float s2 = 0.08838834764831845f * LOG2E;   // (1/sqrt(128))*log2e
  const float slopeL = slopes[h] * LOG2E;

  __shared__ bf16 Kb[4][64 * 128];
  __shared__ bf16 Vb[4][64 * 128];
  __shared__ bf16 P_lds[128 * 64];  // [qrow(128)][k ^ ((qrow&7)<<3)], wave-priv

  const bf16* ksmB = ksm + (size_t)bh * SEQ * 128;
  const bf16* vtB  = vt  + (size_t)bh * SEQ * 128;

  auto stage = [&](int kt, int bsel) {     // 4 loads/thread
#pragma unroll
    for (int j = 0; j < 2; j++) {
      const int c = j * 512 + tid;         // 1024 chunks of 16B
      gld_lds16(ksmB + (size_t)kt * 8192 + c * 8, &Kb[bsel][c * 8]);
      gld_lds16(vtB  + (size_t)kt * 8192 + c * 8, &Vb[bsel][c * 8]);
    }
  };

  auto run_strip = [&](int qtile) {
    const int nt = 2 * qtile + 2;
    int kt0 = 0;
    if (slopeL > 1e-6f) {
      const int W = (int)(64.f / slopeL + 128.f);
      const int wlim = qtile * 128 - W - 63;
      if (wlim > 0) kt0 = (wlim >> 6) & ~1;      // even, >= 0, < nt
    }
    const int iq = qtile * 128 + wid * 16 + l16;   // this lane's q-row
    bf16x8 qf[4];
    {
      const bf16* qrow = qkvp + (size_t)(b * SEQ + iq) * 8192 + h * 128;
#pragma unroll
      for (int kb = 0; kb < 4; kb++) qf[kb] = *(const bf16x8*)(qrow + kb * 32 + l4 * 8);
    }
    f32x4 oacc[8];   // oacc[df][r] = O[iq][df*16 + l4*4 + r]
    const f32x4 z = {0.f, 0.f, 0.f, 0.f};
#pragma unroll
    for (int i = 0; i < 8; i++) oacc[i] = z;
    float m2 = -1e38f, lpart = 0.f;

    auto tile = [&](int t, const bf16* K_, const bf16* V_) {
      f32x4 sacc[4];
#pragma unroll
      for (int jf = 0; jf < 4; jf++) {
        f32x4 a = z;
#pragma unroll
        for (int kb = 0; kb < 4; kb++) {
          bf16x8 kf = *(const bf16x8*)&K_[(jf * 16 + l16) * 128 + ((kb * 32 + l4 * 8) ^ swz)];
          a = __builtin_amdgcn_mfma_f32_16x16x32_bf16(kf, qf[kb], a, 0, 0, 0);
        }
        sacc[jf] = a;
      }

      const bool diag = (t >= 2 * qtile);
      const int kbase = t * 64 + l4 * 4;
#pragma unroll
      for (int jf = 0; jf < 4; jf++) {
#pragma unroll
        for (int r = 0; r < 4; r++) {
          int j = kbase + jf * 16 + r;
          float v = fmaf(sacc[jf][r], s2, (float)j * slopeL);
          if (diag && j > iq) v = -1e38f;
          sacc[jf][r] = v;
        }
      }

      float mx = sacc[0][0];
#pragma unroll
      for (int jf = 0; jf < 4; jf++)
#pragma unroll
        for (int r = 0; r < 4; r++) mx = fmaxf(mx, sacc[jf][r]);
      mx = fmaxf(mx, __shfl_xor(mx, 16, 64));
      mx = fmaxf(mx, __shfl_xor(mx, 32, 64));

      if (__any(mx > m2 + 14.f)) {         // uniform defer-max rescale
        float mnew  = fmaxf(m2, mx);
        float alpha = __builtin_amdgcn_exp2f(m2 - mnew);
        m2 = mnew;
        lpart *= alpha;
#pragma unroll
        for (int df = 0; df < 8; df++) oacc[df] *= alpha;
      }

      float rs = 0.f;
#pragma unroll
      for (int jf = 0; jf < 4; jf++) {
        bf16x4 pw;
#pragma unroll
        for (int r = 0; r < 4; r++) {
          float pe = __builtin_amdgcn_exp2f(sacc[jf][r] - m2);
          rs += pe;
          pw[r] = (bf16)pe;
        }
        *(bf16x4*)&P_lds[(wid * 16 + l16) * 64 + ((jf * 16 + l4 * 4) ^ swz)] = pw;
      }
      lpart += rs;

#pragma unroll
      for (int kb2 = 0; kb2 < 2; ++kb2) {
        bf16x8 pf = *(const bf16x8*)&P_lds[(wid * 16 + l16) * 64 + ((kb2 * 32 + l4 * 8) ^ swz)];
#pragma unroll
        for (int df = 0; df < 8; df++) {
          bf16x8 vf = *(const bf16x8*)&V_[(df * 16 + l16) * 64 + ((kb2 * 32 + l4 * 8) ^ swz)];
          oacc[df] = __builtin_amdgcn_mfma_f32_16x16x32_bf16(vf, pf, oacc[df], 0, 0, 0);
        }
      }
    };

    stage(kt0, kt0 & 3);
    stage(kt0 + 1, (kt0 + 1) & 3);
    for (int tp = kt0; tp < nt; tp += 2) {
      if (tp + 2 < nt) {
        stage(tp + 2, (tp + 2) & 3);
        stage(tp + 3, (tp + 3) & 3);
        asm volatile("s_waitcnt vmcnt(8)" ::: "memory");   // tp, tp+1 landed
      } else {
        asm volatile("s_waitcnt vmcnt(0)" ::: "memory");
      }
      __builtin_amdgcn_sched_barrier(0);
      __builtin_amdgcn_s_barrier();                        // all waves see K/V
      tile(tp,     Kb[tp & 3],       Vb[tp & 3]);
      tile(tp + 1, Kb[(tp + 1) & 3], Vb[(tp + 1) & 3]);
      asm volatile("s_waitcnt lgkmcnt(0)" ::: "memory");   // LDS reads done
      __builtin_amdgcn_s_barrier();                        // before overwrite
    }

    lpart += __shfl_xor(lpart, 16, 64);
    lpart += __shfl_xor(lpart, 32, 64);
    const float linv = 1.f / lpart;
    const bf16* pgrow = qkvp + (size_t)(b * SEQ + iq) * 8192 + 6144 + h * 128;
    bf16* grow = gated + (size_t)(b * SEQ + iq) * 2048 + h * 128;
#pragma unroll
    for (int df = 0; df < 8; df++) {
      const int d0 = df * 16 + l4 * 4;
      bf16x4 pg4 = *(const bf16x4*)(pgrow + d0);
      bf16x4 o4;
#pragma unroll
      for (int r = 0; r < 4; r++) {
        float o  = oacc[df][r] * linv;
        float pg = (float)pg4[r];
        float silu = pg / (1.f + __expf(-pg));
        o4[r] = (bf16)(silu * o);
      }
      *(bf16x4*)(grow + d0) = o4;
    }
  };

  run_strip(15 - pr);    // long strip first
  run_strip(pr);         // short strip re-reads L2-warm K/V
}

// ---------------------------------------------------------------------------
extern "C" void kernel_launch(void* const* d_in, const int* in_sizes, int n_in,
                              void* d_out, int out_size, void* d_ws, size_t ws_size,
                              hipStream_t stream) {
  (void)in_sizes; (void)n_in; (void)out_size; (void)ws_size;
  const float* x      = (const float*)d_in[0];
  const float* w_in   = (const float*)d_in[1];
  const float* w_out  = (const float*)d_in[2];
  const float* lnig   = (const float*)d_in[3];
  const float* lnib   = (const float*)d_in[4];
  const float* lnog   = (const float*)d_in[5];
  const float* lnob   = (const float*)d_in[6];
  const float* slopes = (const float*)d_in[7];
  const float* smf    = (const float*)d_in[8];
  float* out = (float*)d_out;

  char* ws = (char*)d_ws;
  size_t off = 0;
  bf16* hb      = (bf16*)(ws + off); off += (size_t)4096 * 1024 * 2;  // h (bf16)
  bf16* w_in_b  = (bf16*)(ws + off); off += (size_t)8192 * 1024 * 2;
  bf16* w_out_b = (bf16*)(ws + off); off += (size_t)1024 * 2048 * 2;
  bf16* qkvp    = (bf16*)(ws + off); off += (size_t)4096 * 8192 * 2;
  bf16* ksm     = (bf16*)(ws + off); off += (size_t)32 * 2048 * 128 * 2;
  bf16* gated   = (bf16*)(ws + off); off += (size_t)4096 * 2048 * 2;
  bf16* yb0     = (bf16*)(ws + off); off += (size_t)4096 * 1024 * 2;  // bf16 partial
  bf16* yb1     = (bf16*)(ws + off); off += (size_t)4096 * 1024 * 2;  // bf16 partial
  bf16* vt      = yb0;  // alias: vt (16MB) spans yb0+yb1; dead before gemm128

  prepass_kernel<<<9216, 256, 0, stream>>>(x, w_in, w_out, lnig, lnib,
                                           hb, w_in_b, w_out_b);
  gemm256<<<256, 1024, 0, stream>>>(hb, w_in_b, qkvp, 4096, 8192, 1024, 4, 8, 8);
  prep_kernel<<<dim3(32, 32), 256, 0, stream>>>(qkvp, smf, ksm, vt);
  attn_kernel<<<256, 512, 0, stream>>>(qkvp, ksm, vt, slopes, gated);
  gemm128<<<512, 256, 0, stream>>>(gated, w_out_b, yb0, 4096, 1024, 2048, 1, 8, 4);
  ln_kernel<<<4096, 256, 0, stream>>>(yb0, yb1, lnog, lnob, out);
}